// Round 1
// baseline (349.126 us; speedup 1.0000x reference)
//
#include <hip/hip_runtime.h>
#include <math.h>

#define SHEET 160
#define LTOT (SHEET*SHEET)          // 25600
#define AFF_K 15
#define AFF_C 2
#define F_AFF 450
#define LAT_K 25
#define F_LAT 625
#define N_ITERS 10
#define IN_HW 174                   // SHEET + AFF_K - 1
#define HOMEO 0.02f
#define PI_D 3.14159265358979323846

// lateral-kernel tile geometry: one output row, WPB adjacent columns per block
#define WPB 8                       // waves (=locations) per block
#define BLK (WPB*64)                // 512 threads
#define NBLK (LTOT/WPB)             // 3200 blocks
#define TW 56                       // E-tile width  = WPB + 48
#define TH 25                       // E-tile height (y = i + 2r - 24, r=0..24)
#define TILE_N (TW*TH)              // 1400
#define LTW 60                      // L-tile width  = TW + 4
#define LTH 53                      // L-tile height (y = i-26 .. i+26)
#define LT_N (LTW*LTH)              // 3180

// ---- workspace layout (float offsets) ----
#define WS_ENV    0                 // 256 (225 used)  [unused placeholder]
#define WS_SRE    256               // 32 (25 used)
#define WS_AFFTAB 288               // float2[512] = 1024 floats {env, off}
#define WS_LATTAB 1312              // float2[640] = 1280 floats {lri, lds_off}
#define WS_AFF    2592
#define WS_L      (WS_AFF  + LTOT)
#define WS_LM     (WS_L    + LTOT)
#define WS_ISUM   (WS_LM   + LTOT)
#define WS_PART   (WS_ISUM + LTOT)  // NBLK floats

__device__ __forceinline__ float wred(float v) {
    #pragma unroll
    for (int m = 32; m > 0; m >>= 1) v += __shfl_xor(v, m, 64);
    return v;
}

// ---------------- init: constant tables (recomputed every call; deterministic) ----------------
__global__ __launch_bounds__(1024) void k_init(float* __restrict__ ws) {
    __shared__ float red[1024];
    const int t = threadIdx.x;

    // sre raw (5x5 excitation kernel, sum-normalized)
    float sre_raw = 0.f;
    if (t < 25) {
        int u = t / 5, v = t % 5;
        double d = sqrt((double)((u-2)*(u-2) + (v-2)*(v-2)));
        if (d < 2.5) { double cv = cos(fmin(d/5.0, 1.0) * PI_D * 0.5); sre_raw = (float)(cv*cv); }
    }

    // lri raw (25x25 lateral kernel, max-normalized)
    float lri_raw = 0.f;
    const int dy = t / 25, dx = t % 25;
    if (t < 625) {
        double d = sqrt((double)((dy-12)*(dy-12) + (dx-12)*(dx-12)));
        double base = 0.0, inh = 0.0;
        if (d < 12.5) { double cv = cos(fmin(d/25.0, 1.0) * PI_D * 0.5); base = cv*cv; }
        if (d < 1.25) { double cv = cos(fmin(d/2.5,  1.0) * PI_D * 0.5); inh  = cv*cv; }
        lri_raw = (float)(base * (1.0 - inh));
    }

    // max-reduce lri
    red[t] = lri_raw;
    __syncthreads();
    #pragma unroll
    for (int s = 512; s > 0; s >>= 1) {
        if (t < s) red[t] = fmaxf(red[t], red[t + s]);
        __syncthreads();
    }
    const float lri_max = red[0];
    __syncthreads();

    // sum-reduce sre
    red[t] = sre_raw;
    __syncthreads();
    #pragma unroll
    for (int s = 512; s > 0; s >>= 1) {
        if (t < s) red[t] += red[t + s];
        __syncthreads();
    }
    const float sre_sum = red[0];

    if (t < 32) ws[WS_SRE + t] = (t < 25) ? sre_raw / sre_sum : 0.f;

    // lateral table: {lri_norm, LDS element offset dy*TW + 2*dx}
    if (t < 640) {
        float lv = (t < 625) ? lri_raw / lri_max : 0.f;
        int  off = (t < 625) ? (dy * TW + 2 * dx) : 0;
        ((float2*)(ws + WS_LATTAB))[t] = make_float2(lv, __int_as_float(off));
    }

    // afferent table: {env, global x offset c*174*174 + kh*174 + kw}
    if (t < 512) {
        float ev = 0.f; int off = 0;
        if (t < 450) {
            int c  = t / 225, rr = t % 225;
            int kh = rr / 15, kw = rr % 15;
            double d = sqrt((double)((kh-7)*(kh-7) + (kw-7)*(kw-7)));
            if (d < 7.5) { double cv = cos(fmin(d/15.0, 1.0) * PI_D * 0.5); ev = (float)(cv*cv); }
            off = c * (IN_HW*IN_HW) + kh * IN_HW + kw;
        }
        ((float2*)(ws + WS_AFFTAB))[t] = make_float2(ev, __int_as_float(off));
    }
}

// ---------------- afferent pass: wave per location ----------------
__global__ __launch_bounds__(BLK) void k_aff(const float* __restrict__ x,
                                             const float* __restrict__ rfs,
                                             const float* __restrict__ ada,
                                             float* __restrict__ out_rawaff,
                                             float* __restrict__ ws) {
    const float2* tab = (const float2*)(ws + WS_AFFTAB);
    const int w = threadIdx.x >> 6, lane = threadIdx.x & 63;
    const int l = blockIdx.x * WPB + w;
    const int i = l / SHEET, j = l % SHEET;
    const int xbase = i * IN_HW + j;
    const float* rrow = rfs + (size_t)l * F_AFF;

    float dot = 0.f, sum = 0.f;
    #pragma unroll
    for (int it = 0; it < 8; ++it) {
        int f = it * 64 + lane;
        float2 tb = tab[f];
        float  rv = (f < F_AFF) ? rrow[f] : 0.f;
        float  xv = x[xbase + __float_as_int(tb.y)];
        dot = fmaf(xv * tb.x, rv, dot);
        sum += rv;
    }
    dot = wred(dot);
    sum = wred(sum);
    if (lane == 0) {
        float a = dot / sum;
        out_rawaff[l] = 45.0f * a;                 // raw_aff
        float aff = a - ada[l];
        ws[WS_AFF + l] = aff;
        ws[WS_L   + l] = fmaxf(aff, 0.f);          // lat_0 = relu(aff)
        ws[WS_LM  + l] = 0.f;                      // lat_mean accumulator
    }
}

// ---------------- lateral iteration: fused 5x5 conv (halo recompute) + 625-dot ----------------
template<bool FIRST>
__global__ __launch_bounds__(BLK) void k_lat(const float* __restrict__ latw,
                                             float* __restrict__ ws,
                                             const float* __restrict__ lsrc,
                                             float* __restrict__ lat_out) {
    __shared__ float Lt[LT_N];
    __shared__ float Et[TILE_N];
    const int b  = blockIdx.x;
    const int i  = b / (SHEET / WPB);
    const int j0 = (b % (SHEET / WPB)) * WPB;

    // stage L tile (previous lat, pad = HOMEO)
    for (int idx = threadIdx.x; idx < LT_N; idx += BLK) {
        int r = idx / LTW, c = idx % LTW;
        int y  = i  + r - 26;
        int xx = j0 + c - 26;
        Lt[idx] = ((unsigned)y < SHEET && (unsigned)xx < SHEET) ? lsrc[y*SHEET + xx] : HOMEO;
    }
    float sreg[25];
    #pragma unroll
    for (int q = 0; q < 25; ++q) sreg[q] = ws[WS_SRE + q];
    __syncthreads();

    // compute E tile = 5x5 conv, OOB positions = HOMEO (the 24-pad of lp)
    for (int idx = threadIdx.x; idx < TILE_N; idx += BLK) {
        int r = idx / TW, c = idx % TW;
        int y  = i  + 2*r - 24;
        int xx = j0 + c  - 24;
        float val = HOMEO;
        if ((unsigned)y < SHEET && (unsigned)xx < SHEET) {
            float acc = 0.f;
            #pragma unroll
            for (int u = 0; u < 5; ++u)
                #pragma unroll
                for (int v = 0; v < 5; ++v)
                    acc = fmaf(Lt[(2*r + u)*LTW + (c + v)], sreg[u*5 + v], acc);
            val = acc;
        }
        Et[idx] = val;
    }
    __syncthreads();

    const int w = threadIdx.x >> 6, lane = threadIdx.x & 63;
    const int l = i * SHEET + j0 + w;
    const float* wrow = latw + (size_t)l * F_LAT;
    const float2* tab = (const float2*)(ws + WS_LATTAB);

    float acc = 0.f, sum = 0.f;
    #pragma unroll 2
    for (int it = 0; it < 10; ++it) {
        int f = it * 64 + lane;
        float2 tb = tab[f];
        float  wv = (f < F_LAT) ? wrow[f] : 0.f;
        float  e  = Et[__float_as_int(tb.y) + w];
        acc = fmaf(e * tb.x, wv, acc);
        if (FIRST) sum += wv;
    }
    acc = wred(acc);
    if (FIRST) sum = wred(sum);

    if (lane == 0) {
        float inv;
        if (FIRST) { inv = 1.0f / sum; ws[WS_ISUM + l] = inv; }
        else       { inv = ws[WS_ISUM + l]; }
        float lat_neg = acc * inv;                        // lat_w = w / sum
        float ec = Et[12*TW + 24 + w];                    // exc at (i,j)
        float v = ec * 0.45f - lat_neg * 0.55f + ws[WS_AFF + l];
        v = tanhf(fmaxf(v, 0.f));
        lat_out[l] = v;
        ws[WS_LM + l] += v;
    }
}

// ---------------- hebbian correlation: per-block partials ----------------
__global__ __launch_bounds__(BLK) void k_hebb(const float* __restrict__ latw,
                                              float* __restrict__ ws) {
    __shared__ float Gt[TILE_N];
    __shared__ float part[WPB];
    const int b  = blockIdx.x;
    const int i  = b / (SHEET / WPB);
    const int j0 = (b % (SHEET / WPB)) * WPB;
    const float* lm = ws + WS_LM;

    // stage lat_mean tile (scaled by 1/10), pad = HOMEO
    for (int idx = threadIdx.x; idx < TILE_N; idx += BLK) {
        int r = idx / TW, c = idx % TW;
        int y  = i  + 2*r - 24;
        int xx = j0 + c  - 24;
        Gt[idx] = ((unsigned)y < SHEET && (unsigned)xx < SHEET) ? lm[y*SHEET + xx] * 0.1f : HOMEO;
    }
    __syncthreads();

    const int w = threadIdx.x >> 6, lane = threadIdx.x & 63;
    const int l = i * SHEET + j0 + w;
    const float* wrow = latw + (size_t)l * F_LAT;
    const float2* tab = (const float2*)(ws + WS_LATTAB);

    float acc = 0.f;
    #pragma unroll 2
    for (int it = 0; it < 10; ++it) {
        int f = it * 64 + lane;
        float2 tb = tab[f];
        float  wv = (f < F_LAT) ? wrow[f] : 0.f;
        float  e  = Gt[__float_as_int(tb.y) + w];
        acc = fmaf(e * tb.x, wv, acc);
    }
    acc = wred(acc);
    if (lane == 0) {
        float lmv = Gt[12*TW + 24 + w];                   // lat_mean[l] (already *0.1)
        part[w] = lmv * 62.5f * ws[WS_ISUM + l] * acc;    // latw_n = w*62.5/sum
    }
    __syncthreads();
    if (threadIdx.x == 0) {
        float s = 0.f;
        #pragma unroll
        for (int q = 0; q < WPB; ++q) s += part[q];
        ws[WS_PART + b] = s;
    }
}

// ---------------- deterministic final reduce ----------------
__global__ __launch_bounds__(1024) void k_final(const float* __restrict__ ws,
                                                float* __restrict__ out_scalar) {
    __shared__ float red[1024];
    float s = 0.f;
    for (int idx = threadIdx.x; idx < NBLK; idx += 1024) s += ws[WS_PART + idx];
    red[threadIdx.x] = s;
    __syncthreads();
    #pragma unroll
    for (int st = 512; st > 0; st >>= 1) {
        if (threadIdx.x < st) red[threadIdx.x] += red[threadIdx.x + st];
        __syncthreads();
    }
    if (threadIdx.x == 0) *out_scalar = red[0];
}

extern "C" void kernel_launch(void* const* d_in, const int* in_sizes, int n_in,
                              void* d_out, int out_size, void* d_ws, size_t ws_size,
                              hipStream_t stream) {
    const float* x    = (const float*)d_in[0];
    const float* rfs  = (const float*)d_in[1];
    const float* latw = (const float*)d_in[2];
    const float* ada  = (const float*)d_in[3];
    float* out = (float*)d_out;
    float* ws  = (float*)d_ws;

    k_init<<<1, 1024, 0, stream>>>(ws);
    k_aff<<<NBLK, BLK, 0, stream>>>(x, rfs, ada, out, ws);

    for (int t = 0; t < N_ITERS; ++t) {
        float* lat_out = (t == N_ITERS - 1) ? (out + LTOT) : (ws + WS_L);
        if (t == 0) k_lat<true ><<<NBLK, BLK, 0, stream>>>(latw, ws, ws + WS_L, lat_out);
        else        k_lat<false><<<NBLK, BLK, 0, stream>>>(latw, ws, ws + WS_L, lat_out);
    }

    k_hebb<<<NBLK, BLK, 0, stream>>>(latw, ws);
    k_final<<<1, 1024, 0, stream>>>(ws, out + 2 * LTOT);
}

// Round 2
// 221.990 us; speedup vs baseline: 1.5727x; 1.5727x over previous
//
#include <hip/hip_runtime.h>
#include <math.h>

#define SHEET 160
#define LTOT (SHEET*SHEET)          // 25600
#define AFF_K 15
#define AFF_C 2
#define F_AFF 450
#define F_LAT 625
#define N_ITERS 10
#define IN_HW 174                   // SHEET + AFF_K - 1
#define HOMEO 0.02f
#define PI_D 3.14159265358979323846

// ---- lateral tile geometry: 4 rows x 16 cols of locations per block ----
#define BH 4
#define BW 16
#define LOCS (BH*BW)                // 64 locations/block
#define BLK 512                     // 8 waves, each handles 8 locations
#define GRID_L ((SHEET/BH)*(SHEET/BW))  // 40*10 = 400 blocks
#define EH 52                       // BH + 48 E-field rows
#define EWH 33                      // (BW+48)/2 + 1 pad (parity-half width)
#define EP_HALF (EH*EWH)            // 1716
#define EP_N (2*EP_HALF)            // 3432
#define LW 69                       // BW+52=68 cols, padded to 69 (odd -> bank spread)
#define LH 56                       // BH + 52
#define LT_N (LH*LW)                // 3864

// afferent kernel geometry (unchanged from r1)
#define AWPB 8
#define ABLK (AWPB*64)
#define ANBLK (LTOT/AWPB)

// ---- workspace layout (float offsets) ----
#define WS_SRE    0                 // 32 (25 used)
#define WS_LATTAB 32                // float2[640] = 1280 floats {lri, off66}
#define WS_AFFTAB 1312              // float2[512] = 1024 floats {env, off}
#define WS_AFF    2336
#define WS_L0     (WS_AFF  + LTOT)
#define WS_L1     (WS_L0   + LTOT)
#define WS_LM     (WS_L1   + LTOT)
#define WS_ISUM   (WS_LM   + LTOT)
#define WS_PART   (WS_ISUM + LTOT)  // GRID_L floats

__device__ __forceinline__ float wred(float v) {
    #pragma unroll
    for (int m = 32; m > 0; m >>= 1) v += __shfl_xor(v, m, 64);
    return v;
}

// ---------------- init: constant tables (recomputed every call; deterministic) ----------------
__global__ __launch_bounds__(1024) void k_init(float* __restrict__ ws) {
    __shared__ float red[1024];
    const int t = threadIdx.x;

    // sre raw (5x5 excitation kernel, sum-normalized)
    float sre_raw = 0.f;
    if (t < 25) {
        int u = t / 5, v = t % 5;
        double d = sqrt((double)((u-2)*(u-2) + (v-2)*(v-2)));
        if (d < 2.5) { double cv = cos(fmin(d/5.0, 1.0) * PI_D * 0.5); sre_raw = (float)(cv*cv); }
    }

    // lri raw (25x25 lateral kernel, max-normalized)
    float lri_raw = 0.f;
    const int dy = t / 25, dx = t % 25;
    if (t < 625) {
        double d = sqrt((double)((dy-12)*(dy-12) + (dx-12)*(dx-12)));
        double base = 0.0, inh = 0.0;
        if (d < 12.5) { double cv = cos(fmin(d/25.0, 1.0) * PI_D * 0.5); base = cv*cv; }
        if (d < 1.25) { double cv = cos(fmin(d/2.5,  1.0) * PI_D * 0.5); inh  = cv*cv; }
        lri_raw = (float)(base * (1.0 - inh));
    }

    // max-reduce lri
    red[t] = lri_raw;
    __syncthreads();
    #pragma unroll
    for (int s = 512; s > 0; s >>= 1) {
        if (t < s) red[t] = fmaxf(red[t], red[t + s]);
        __syncthreads();
    }
    const float lri_max = red[0];
    __syncthreads();

    // sum-reduce sre
    red[t] = sre_raw;
    __syncthreads();
    #pragma unroll
    for (int s = 512; s > 0; s >>= 1) {
        if (t < s) red[t] += red[t + s];
        __syncthreads();
    }
    const float sre_sum = red[0];

    if (t < 32) ws[WS_SRE + t] = (t < 25) ? sre_raw / sre_sum : 0.f;

    // lateral table: {lri_norm, gather offset dy*66 + dx} (row stride 2*EWH=66 in parity half)
    if (t < 640) {
        float lv = (t < 625) ? lri_raw / lri_max : 0.f;
        int  off = (t < 625) ? (dy * (2*EWH) + dx) : 0;
        ((float2*)(ws + WS_LATTAB))[t] = make_float2(lv, __int_as_float(off));
    }

    // afferent table: {env, global x offset c*174*174 + kh*174 + kw}
    if (t < 512) {
        float ev = 0.f; int off = 0;
        if (t < 450) {
            int c  = t / 225, rr = t % 225;
            int kh = rr / 15, kw = rr % 15;
            double d = sqrt((double)((kh-7)*(kh-7) + (kw-7)*(kw-7)));
            if (d < 7.5) { double cv = cos(fmin(d/15.0, 1.0) * PI_D * 0.5); ev = (float)(cv*cv); }
            off = c * (IN_HW*IN_HW) + kh * IN_HW + kw;
        }
        ((float2*)(ws + WS_AFFTAB))[t] = make_float2(ev, __int_as_float(off));
    }
}

// ---------------- afferent pass: wave per location ----------------
__global__ __launch_bounds__(ABLK) void k_aff(const float* __restrict__ x,
                                              const float* __restrict__ rfs,
                                              const float* __restrict__ ada,
                                              float* __restrict__ out_rawaff,
                                              float* __restrict__ ws) {
    const float2* tab = (const float2*)(ws + WS_AFFTAB);
    const int w = threadIdx.x >> 6, lane = threadIdx.x & 63;
    const int l = blockIdx.x * AWPB + w;
    const int i = l / SHEET, j = l % SHEET;
    const int xbase = i * IN_HW + j;
    const float* rrow = rfs + (size_t)l * F_AFF;

    float dot = 0.f, sum = 0.f;
    #pragma unroll
    for (int it = 0; it < 8; ++it) {
        int f = it * 64 + lane;
        float2 tb = tab[f];
        int   fc = (f < F_AFF) ? f : (F_AFF - 1);
        float rv = rrow[fc];
        if (f >= F_AFF) rv = 0.f;
        float xv = x[xbase + __float_as_int(tb.y)];
        dot = fmaf(xv * tb.x, rv, dot);
        sum += rv;
    }
    dot = wred(dot);
    sum = wred(sum);
    if (lane == 0) {
        float a = dot / sum;
        out_rawaff[l] = 45.0f * a;                 // raw_aff
        float aff = a - ada[l];
        ws[WS_AFF + l] = aff;
        ws[WS_L0  + l] = fmaxf(aff, 0.f);          // lat_0 = relu(aff)
        ws[WS_LM  + l] = 0.f;                      // lat_mean accumulator
    }
}

// ---------------- lateral iteration: fused 5x5 conv (2D tile) + 625-dot ----------------
template<bool FIRST>
__global__ __launch_bounds__(BLK, 4) void k_lat(const float* __restrict__ latw,
                                                float* __restrict__ ws,
                                                const float* __restrict__ lsrc,
                                                float* __restrict__ lat_out) {
    __shared__ float Lt[LT_N];
    __shared__ float Ep[EP_N];
    const int b  = blockIdx.x;
    const int i0 = (b / (SHEET/BW)) * BH;
    const int j0 = (b % (SHEET/BW)) * BW;
    const int tid = threadIdx.x;
    const int w = tid >> 6, lane = tid & 63;

    const float* sre_g = ws + WS_SRE;   // uniform -> s_loads

    // ---- stage L tile (previous lat, pad = HOMEO), 56 x 68 (width padded to 69) ----
    for (int idx = tid; idx < LT_N; idx += BLK) {
        int r = idx / LW, c = idx - r * LW;
        int y  = i0 + r - 26;
        int xx = j0 + c - 26;
        float v = HOMEO;
        if (c < 68 && (unsigned)y < SHEET && (unsigned)xx < SHEET) v = lsrc[y*SHEET + xx];
        Lt[idx] = v;
    }

    // ---- preload per-lane gather table (shared by all 8 locations of this wave) ----
    const float2* tab = (const float2*)(ws + WS_LATTAB);
    float lri_reg[10]; int off_reg[10];
    #pragma unroll
    for (int it = 0; it < 10; ++it) {
        float2 tb = tab[it * 64 + lane];
        lri_reg[it] = tb.x;
        off_reg[it] = __float_as_int(tb.y);
    }
    __syncthreads();

    // ---- conv 5x5 -> E field, 4-wide register blocked, parity-split store ----
    for (int qi = tid; qi < EH * 16; qi += BLK) {      // 832 quads
        int q = qi & 15, y = qi >> 4;
        int x0 = q * 4;
        float a0 = 0.f, a1 = 0.f, a2 = 0.f, a3 = 0.f;
        #pragma unroll
        for (int u = 0; u < 5; ++u) {
            const float* row = &Lt[(y + u) * LW + x0];
            float ra[8];
            #pragma unroll
            for (int v = 0; v < 8; ++v) ra[v] = row[v];
            #pragma unroll
            for (int v = 0; v < 5; ++v) {
                float s = sre_g[u * 5 + v];
                a0 = fmaf(ra[v],     s, a0);
                a1 = fmaf(ra[v + 1], s, a1);
                a2 = fmaf(ra[v + 2], s, a2);
                a3 = fmaf(ra[v + 3], s, a3);
            }
        }
        int yg = i0 - 24 + y;
        bool yok = (unsigned)yg < SHEET;
        int xg = j0 - 24 + x0;
        float v0 = (yok && (unsigned)(xg    ) < SHEET) ? a0 : HOMEO;
        float v1 = (yok && (unsigned)(xg + 1) < SHEET) ? a1 : HOMEO;
        float v2 = (yok && (unsigned)(xg + 2) < SHEET) ? a2 : HOMEO;
        float v3 = (yok && (unsigned)(xg + 3) < SHEET) ? a3 : HOMEO;
        // parity split: x_l = x0+k -> half k&1, col (x0+k)>>1 = 2q + (k>>1)
        int c0 = y * EWH + 2 * q;
        Ep[c0]                   = v0;
        Ep[EP_HALF + c0]         = v1;
        Ep[c0 + 1]               = v2;
        Ep[EP_HALF + c0 + 1]     = v3;
    }
    __syncthreads();

    // ---- per-location 625-dot: wave handles 8 locations ----
    #pragma unroll 2
    for (int s = 0; s < 8; ++s) {
        int li = w * 8 + s;
        int r  = li >> 4, cc = li & 15;
        int l  = (i0 + r) * SHEET + (j0 + cc);
        const float* wrow = latw + (size_t)l * F_LAT;
        int gbase = (cc & 1) * EP_HALF + r * EWH + (cc >> 1);

        float acc = 0.f, sum = 0.f;
        #pragma unroll
        for (int it = 0; it < 10; ++it) {
            int f  = it * 64 + lane;
            int fc = (f < F_LAT) ? f : (F_LAT - 1);
            float wv = wrow[fc];
            if (f >= F_LAT) wv = 0.f;
            float e = Ep[gbase + off_reg[it]];
            acc = fmaf(e * lri_reg[it], wv, acc);
            if (FIRST) sum += wv;
        }
        acc = wred(acc);
        if (FIRST) sum = wred(sum);

        if (lane == 0) {
            float inv;
            if (FIRST) { inv = 1.0f / sum; ws[WS_ISUM + l] = inv; }
            else       { inv = ws[WS_ISUM + l]; }
            float lat_neg = acc * inv;
            float ec = Ep[(cc & 1) * EP_HALF + (r + 24) * EWH + (cc >> 1) + 12];
            float v = ec * 0.45f - lat_neg * 0.55f + ws[WS_AFF + l];
            v = tanhf(fmaxf(v, 0.f));
            lat_out[l] = v;
            ws[WS_LM + l] += v;
        }
    }
}

// ---------------- hebbian correlation: same 2D tiling, no conv ----------------
__global__ __launch_bounds__(BLK, 4) void k_hebb(const float* __restrict__ latw,
                                                 float* __restrict__ ws) {
    __shared__ float LMp[EP_N];
    __shared__ float part[8];
    const int b  = blockIdx.x;
    const int i0 = (b / (SHEET/BW)) * BH;
    const int j0 = (b % (SHEET/BW)) * BW;
    const int tid = threadIdx.x;
    const int w = tid >> 6, lane = tid & 63;
    const float* lm = ws + WS_LM;

    // stage lat_mean tile (scaled by 1/10) in parity-split layout, pad = HOMEO
    for (int idx = tid; idx < EP_N; idx += BLK) {
        int p   = idx / EP_HALF;
        int rem = idx - p * EP_HALF;
        int y   = rem / EWH;
        int col = rem - y * EWH;
        int yg = i0 - 24 + y;
        int xg = j0 - 24 + 2 * col + p;
        float v = HOMEO;
        if ((unsigned)yg < SHEET && (unsigned)xg < SHEET) v = lm[yg*SHEET + xg] * 0.1f;
        LMp[idx] = v;
    }

    const float2* tab = (const float2*)(ws + WS_LATTAB);
    float lri_reg[10]; int off_reg[10];
    #pragma unroll
    for (int it = 0; it < 10; ++it) {
        float2 tb = tab[it * 64 + lane];
        lri_reg[it] = tb.x;
        off_reg[it] = __float_as_int(tb.y);
    }
    __syncthreads();

    float wacc = 0.f;   // lane0 accumulates its wave's 8 location terms
    #pragma unroll 2
    for (int s = 0; s < 8; ++s) {
        int li = w * 8 + s;
        int r  = li >> 4, cc = li & 15;
        int l  = (i0 + r) * SHEET + (j0 + cc);
        const float* wrow = latw + (size_t)l * F_LAT;
        int gbase = (cc & 1) * EP_HALF + r * EWH + (cc >> 1);

        float acc = 0.f;
        #pragma unroll
        for (int it = 0; it < 10; ++it) {
            int f  = it * 64 + lane;
            int fc = (f < F_LAT) ? f : (F_LAT - 1);
            float wv = wrow[fc];
            if (f >= F_LAT) wv = 0.f;
            float e = LMp[gbase + off_reg[it]];
            acc = fmaf(e * lri_reg[it], wv, acc);
        }
        acc = wred(acc);
        if (lane == 0) {
            float lmv = LMp[(cc & 1) * EP_HALF + (r + 24) * EWH + (cc >> 1) + 12];
            wacc += lmv * 62.5f * ws[WS_ISUM + l] * acc;
        }
    }
    if (lane == 0) part[w] = wacc;
    __syncthreads();
    if (tid == 0) {
        float s = 0.f;
        #pragma unroll
        for (int q = 0; q < 8; ++q) s += part[q];
        ws[WS_PART + b] = s;
    }
}

// ---------------- deterministic final reduce ----------------
__global__ __launch_bounds__(1024) void k_final(const float* __restrict__ ws,
                                                float* __restrict__ out_scalar) {
    __shared__ float red[1024];
    float s = 0.f;
    for (int idx = threadIdx.x; idx < GRID_L; idx += 1024) s += ws[WS_PART + idx];
    red[threadIdx.x] = s;
    __syncthreads();
    #pragma unroll
    for (int st = 512; st > 0; st >>= 1) {
        if (threadIdx.x < st) red[threadIdx.x] += red[threadIdx.x + st];
        __syncthreads();
    }
    if (threadIdx.x == 0) *out_scalar = red[0];
}

extern "C" void kernel_launch(void* const* d_in, const int* in_sizes, int n_in,
                              void* d_out, int out_size, void* d_ws, size_t ws_size,
                              hipStream_t stream) {
    const float* x    = (const float*)d_in[0];
    const float* rfs  = (const float*)d_in[1];
    const float* latw = (const float*)d_in[2];
    const float* ada  = (const float*)d_in[3];
    float* out = (float*)d_out;
    float* ws  = (float*)d_ws;

    k_init<<<1, 1024, 0, stream>>>(ws);
    k_aff<<<ANBLK, ABLK, 0, stream>>>(x, rfs, ada, out, ws);

    // ping-pong lat buffers to avoid cross-block read/write race
    for (int t = 0; t < N_ITERS; ++t) {
        const float* src = ws + ((t & 1) ? WS_L1 : WS_L0);
        float* dst = (t == N_ITERS - 1) ? (out + LTOT)
                                        : (ws + ((t & 1) ? WS_L0 : WS_L1));
        if (t == 0) k_lat<true ><<<GRID_L, BLK, 0, stream>>>(latw, ws, src, dst);
        else        k_lat<false><<<GRID_L, BLK, 0, stream>>>(latw, ws, src, dst);
    }

    k_hebb<<<GRID_L, BLK, 0, stream>>>(latw, ws);
    k_final<<<1, 1024, 0, stream>>>(ws, out + 2 * LTOT);
}

// Round 3
// 221.822 us; speedup vs baseline: 1.5739x; 1.0008x over previous
//
#include <hip/hip_runtime.h>
#include <math.h>

#define SHEET 160
#define LTOT (SHEET*SHEET)          // 25600
#define AFF_K 15
#define AFF_C 2
#define F_AFF 450
#define F_LAT 625
#define N_ITERS 10
#define IN_HW 174                   // SHEET + AFF_K - 1
#define HOMEO 0.02f
#define PI_D 3.14159265358979323846

// ---- lateral tile geometry: 4 rows x 16 cols of locations per block ----
#define BH 4
#define BW 16
#define LOCS (BH*BW)                // 64 locations/block
#define BLK 512                     // 8 waves, each handles 8 locations
#define GRID_L ((SHEET/BH)*(SHEET/BW))  // 40*10 = 400 blocks
#define EH 52                       // BH + 48 E-field rows
#define EWH 33                      // (BW+48)/2 + 1 pad (parity-half width)
#define EP_HALF (EH*EWH)            // 1716
#define EP_N (2*EP_HALF)            // 3432
#define LW 69                       // BW+52=68 cols, padded to 69 (odd -> bank spread)
#define LH 56                       // BH + 52
#define LT_N (LH*LW)                // 3864

// afferent kernel geometry (unchanged from r1)
#define AWPB 8
#define ABLK (AWPB*64)
#define ANBLK (LTOT/AWPB)

// ---- workspace layout (float offsets) ----
#define WS_SRE    0                 // 32 (25 used)
#define WS_LATTAB 32                // float2[640] = 1280 floats {lri, off66}
#define WS_AFFTAB 1312              // float2[512] = 1024 floats {env, off}
#define WS_AFF    2336
#define WS_L0     (WS_AFF  + LTOT)
#define WS_L1     (WS_L0   + LTOT)
#define WS_LM     (WS_L1   + LTOT)
#define WS_ISUM   (WS_LM   + LTOT)
#define WS_PART   (WS_ISUM + LTOT)  // GRID_L floats

__device__ __forceinline__ float wred(float v) {
    #pragma unroll
    for (int m = 32; m > 0; m >>= 1) v += __shfl_xor(v, m, 64);
    return v;
}

// ---------------- init: constant tables (recomputed every call; deterministic) ----------------
__global__ __launch_bounds__(1024) void k_init(float* __restrict__ ws) {
    __shared__ float red[1024];
    const int t = threadIdx.x;

    // sre raw (5x5 excitation kernel, sum-normalized)
    float sre_raw = 0.f;
    if (t < 25) {
        int u = t / 5, v = t % 5;
        double d = sqrt((double)((u-2)*(u-2) + (v-2)*(v-2)));
        if (d < 2.5) { double cv = cos(fmin(d/5.0, 1.0) * PI_D * 0.5); sre_raw = (float)(cv*cv); }
    }

    // lri raw (25x25 lateral kernel, max-normalized)
    float lri_raw = 0.f;
    const int dy = t / 25, dx = t % 25;
    if (t < 625) {
        double d = sqrt((double)((dy-12)*(dy-12) + (dx-12)*(dx-12)));
        double base = 0.0, inh = 0.0;
        if (d < 12.5) { double cv = cos(fmin(d/25.0, 1.0) * PI_D * 0.5); base = cv*cv; }
        if (d < 1.25) { double cv = cos(fmin(d/2.5,  1.0) * PI_D * 0.5); inh  = cv*cv; }
        lri_raw = (float)(base * (1.0 - inh));
    }

    // max-reduce lri
    red[t] = lri_raw;
    __syncthreads();
    #pragma unroll
    for (int s = 512; s > 0; s >>= 1) {
        if (t < s) red[t] = fmaxf(red[t], red[t + s]);
        __syncthreads();
    }
    const float lri_max = red[0];
    __syncthreads();

    // sum-reduce sre
    red[t] = sre_raw;
    __syncthreads();
    #pragma unroll
    for (int s = 512; s > 0; s >>= 1) {
        if (t < s) red[t] += red[t + s];
        __syncthreads();
    }
    const float sre_sum = red[0];

    if (t < 32) ws[WS_SRE + t] = (t < 25) ? sre_raw / sre_sum : 0.f;

    // lateral table: {lri_norm, gather offset dy*66 + dx} (row stride 2*EWH=66 in parity half)
    if (t < 640) {
        float lv = (t < 625) ? lri_raw / lri_max : 0.f;
        int  off = (t < 625) ? (dy * (2*EWH) + dx) : 0;
        ((float2*)(ws + WS_LATTAB))[t] = make_float2(lv, __int_as_float(off));
    }

    // afferent table: {env, global x offset c*174*174 + kh*174 + kw}
    if (t < 512) {
        float ev = 0.f; int off = 0;
        if (t < 450) {
            int c  = t / 225, rr = t % 225;
            int kh = rr / 15, kw = rr % 15;
            double d = sqrt((double)((kh-7)*(kh-7) + (kw-7)*(kw-7)));
            if (d < 7.5) { double cv = cos(fmin(d/15.0, 1.0) * PI_D * 0.5); ev = (float)(cv*cv); }
            off = c * (IN_HW*IN_HW) + kh * IN_HW + kw;
        }
        ((float2*)(ws + WS_AFFTAB))[t] = make_float2(ev, __int_as_float(off));
    }
}

// ---------------- afferent pass: wave per location ----------------
__global__ __launch_bounds__(ABLK) void k_aff(const float* __restrict__ x,
                                              const float* __restrict__ rfs,
                                              const float* __restrict__ ada,
                                              float* __restrict__ out_rawaff,
                                              float* __restrict__ ws) {
    const float2* tab = (const float2*)(ws + WS_AFFTAB);
    const int w = threadIdx.x >> 6, lane = threadIdx.x & 63;
    const int l = blockIdx.x * AWPB + w;
    const int i = l / SHEET, j = l % SHEET;
    const int xbase = i * IN_HW + j;
    const float* rrow = rfs + (size_t)l * F_AFF;

    float dot = 0.f, sum = 0.f;
    #pragma unroll
    for (int it = 0; it < 8; ++it) {
        int f = it * 64 + lane;
        float2 tb = tab[f];
        int   fc = (f < F_AFF) ? f : (F_AFF - 1);
        float rv = rrow[fc];
        if (f >= F_AFF) rv = 0.f;
        float xv = x[xbase + __float_as_int(tb.y)];
        dot = fmaf(xv * tb.x, rv, dot);
        sum += rv;
    }
    dot = wred(dot);
    sum = wred(sum);
    if (lane == 0) {
        float a = dot / sum;
        out_rawaff[l] = 45.0f * a;                 // raw_aff
        float aff = a - ada[l];
        ws[WS_AFF + l] = aff;
        ws[WS_L0  + l] = fmaxf(aff, 0.f);          // lat_0 = relu(aff)
        ws[WS_LM  + l] = 0.f;                      // lat_mean accumulator
    }
}

// ---------------- lateral iteration: fused 5x5 conv (2D tile) + 625-dot ----------------
template<bool FIRST>
__global__ __launch_bounds__(BLK, 4) void k_lat(const float* __restrict__ latw,
                                                float* __restrict__ ws,
                                                const float* __restrict__ lsrc,
                                                float* __restrict__ lat_out) {
    __shared__ float Lt[LT_N];
    __shared__ float Ep[EP_N];
    const int b  = blockIdx.x;
    const int i0 = (b / (SHEET/BW)) * BH;
    const int j0 = (b % (SHEET/BW)) * BW;
    const int tid = threadIdx.x;
    const int w = tid >> 6, lane = tid & 63;

    const float* sre_g = ws + WS_SRE;   // uniform -> s_loads

    // ---- stage L tile (previous lat, pad = HOMEO), 56 x 68 (width padded to 69) ----
    for (int idx = tid; idx < LT_N; idx += BLK) {
        int r = idx / LW, c = idx - r * LW;
        int y  = i0 + r - 26;
        int xx = j0 + c - 26;
        float v = HOMEO;
        if (c < 68 && (unsigned)y < SHEET && (unsigned)xx < SHEET) v = lsrc[y*SHEET + xx];
        Lt[idx] = v;
    }

    // ---- preload per-lane gather table (shared by all 8 locations of this wave) ----
    const float2* tab = (const float2*)(ws + WS_LATTAB);
    float lri_reg[10]; int off_reg[10];
    #pragma unroll
    for (int it = 0; it < 10; ++it) {
        float2 tb = tab[it * 64 + lane];
        lri_reg[it] = tb.x;
        off_reg[it] = __float_as_int(tb.y);
    }
    __syncthreads();

    // ---- conv 5x5 -> E field, 4-wide register blocked, parity-split store ----
    for (int qi = tid; qi < EH * 16; qi += BLK) {      // 832 quads
        int q = qi & 15, y = qi >> 4;
        int x0 = q * 4;
        float a0 = 0.f, a1 = 0.f, a2 = 0.f, a3 = 0.f;
        #pragma unroll
        for (int u = 0; u < 5; ++u) {
            const float* row = &Lt[(y + u) * LW + x0];
            float ra[8];
            #pragma unroll
            for (int v = 0; v < 8; ++v) ra[v] = row[v];
            #pragma unroll
            for (int v = 0; v < 5; ++v) {
                float s = sre_g[u * 5 + v];
                a0 = fmaf(ra[v],     s, a0);
                a1 = fmaf(ra[v + 1], s, a1);
                a2 = fmaf(ra[v + 2], s, a2);
                a3 = fmaf(ra[v + 3], s, a3);
            }
        }
        int yg = i0 - 24 + y;
        bool yok = (unsigned)yg < SHEET;
        int xg = j0 - 24 + x0;
        float v0 = (yok && (unsigned)(xg    ) < SHEET) ? a0 : HOMEO;
        float v1 = (yok && (unsigned)(xg + 1) < SHEET) ? a1 : HOMEO;
        float v2 = (yok && (unsigned)(xg + 2) < SHEET) ? a2 : HOMEO;
        float v3 = (yok && (unsigned)(xg + 3) < SHEET) ? a3 : HOMEO;
        // parity split: x_l = x0+k -> half k&1, col (x0+k)>>1 = 2q + (k>>1)
        int c0 = y * EWH + 2 * q;
        Ep[c0]                   = v0;
        Ep[EP_HALF + c0]         = v1;
        Ep[c0 + 1]               = v2;
        Ep[EP_HALF + c0 + 1]     = v3;
    }
    __syncthreads();

    // ---- per-location 625-dot: wave handles 8 locations ----
    #pragma unroll 2
    for (int s = 0; s < 8; ++s) {
        int li = w * 8 + s;
        int r  = li >> 4, cc = li & 15;
        int l  = (i0 + r) * SHEET + (j0 + cc);
        const float* wrow = latw + (size_t)l * F_LAT;
        int gbase = (cc & 1) * EP_HALF + r * EWH + (cc >> 1);

        float acc = 0.f, sum = 0.f;
        #pragma unroll
        for (int it = 0; it < 10; ++it) {
            int f  = it * 64 + lane;
            int fc = (f < F_LAT) ? f : (F_LAT - 1);
            float wv = wrow[fc];
            if (f >= F_LAT) wv = 0.f;
            float e = Ep[gbase + off_reg[it]];
            acc = fmaf(e * lri_reg[it], wv, acc);
            if (FIRST) sum += wv;
        }
        acc = wred(acc);
        if (FIRST) sum = wred(sum);

        if (lane == 0) {
            float inv;
            if (FIRST) { inv = 1.0f / sum; ws[WS_ISUM + l] = inv; }
            else       { inv = ws[WS_ISUM + l]; }
            float lat_neg = acc * inv;
            float ec = Ep[(cc & 1) * EP_HALF + (r + 24) * EWH + (cc >> 1) + 12];
            float v = ec * 0.45f - lat_neg * 0.55f + ws[WS_AFF + l];
            v = tanhf(fmaxf(v, 0.f));
            lat_out[l] = v;
            ws[WS_LM + l] += v;
        }
    }
}

// ---------------- hebbian correlation: same 2D tiling, no conv ----------------
__global__ __launch_bounds__(BLK, 4) void k_hebb(const float* __restrict__ latw,
                                                 float* __restrict__ ws) {
    __shared__ float LMp[EP_N];
    __shared__ float part[8];
    const int b  = blockIdx.x;
    const int i0 = (b / (SHEET/BW)) * BH;
    const int j0 = (b % (SHEET/BW)) * BW;
    const int tid = threadIdx.x;
    const int w = tid >> 6, lane = tid & 63;
    const float* lm = ws + WS_LM;

    // stage lat_mean tile (scaled by 1/10) in parity-split layout, pad = HOMEO
    for (int idx = tid; idx < EP_N; idx += BLK) {
        int p   = idx / EP_HALF;
        int rem = idx - p * EP_HALF;
        int y   = rem / EWH;
        int col = rem - y * EWH;
        int yg = i0 - 24 + y;
        int xg = j0 - 24 + 2 * col + p;
        float v = HOMEO;
        if ((unsigned)yg < SHEET && (unsigned)xg < SHEET) v = lm[yg*SHEET + xg] * 0.1f;
        LMp[idx] = v;
    }

    const float2* tab = (const float2*)(ws + WS_LATTAB);
    float lri_reg[10]; int off_reg[10];
    #pragma unroll
    for (int it = 0; it < 10; ++it) {
        float2 tb = tab[it * 64 + lane];
        lri_reg[it] = tb.x;
        off_reg[it] = __float_as_int(tb.y);
    }
    __syncthreads();

    float wacc = 0.f;   // lane0 accumulates its wave's 8 location terms
    #pragma unroll 2
    for (int s = 0; s < 8; ++s) {
        int li = w * 8 + s;
        int r  = li >> 4, cc = li & 15;
        int l  = (i0 + r) * SHEET + (j0 + cc);
        const float* wrow = latw + (size_t)l * F_LAT;
        int gbase = (cc & 1) * EP_HALF + r * EWH + (cc >> 1);

        float acc = 0.f;
        #pragma unroll
        for (int it = 0; it < 10; ++it) {
            int f  = it * 64 + lane;
            int fc = (f < F_LAT) ? f : (F_LAT - 1);
            float wv = wrow[fc];
            if (f >= F_LAT) wv = 0.f;
            float e = LMp[gbase + off_reg[it]];
            acc = fmaf(e * lri_reg[it], wv, acc);
        }
        acc = wred(acc);
        if (lane == 0) {
            float lmv = LMp[(cc & 1) * EP_HALF + (r + 24) * EWH + (cc >> 1) + 12];
            wacc += lmv * 62.5f * ws[WS_ISUM + l] * acc;
        }
    }
    if (lane == 0) part[w] = wacc;
    __syncthreads();
    if (tid == 0) {
        float s = 0.f;
        #pragma unroll
        for (int q = 0; q < 8; ++q) s += part[q];
        ws[WS_PART + b] = s;
    }
}

// ---------------- deterministic final reduce ----------------
__global__ __launch_bounds__(1024) void k_final(const float* __restrict__ ws,
                                                float* __restrict__ out_scalar) {
    __shared__ float red[1024];
    float s = 0.f;
    for (int idx = threadIdx.x; idx < GRID_L; idx += 1024) s += ws[WS_PART + idx];
    red[threadIdx.x] = s;
    __syncthreads();
    #pragma unroll
    for (int st = 512; st > 0; st >>= 1) {
        if (threadIdx.x < st) red[threadIdx.x] += red[threadIdx.x + st];
        __syncthreads();
    }
    if (threadIdx.x == 0) *out_scalar = red[0];
}

extern "C" void kernel_launch(void* const* d_in, const int* in_sizes, int n_in,
                              void* d_out, int out_size, void* d_ws, size_t ws_size,
                              hipStream_t stream) {
    const float* x    = (const float*)d_in[0];
    const float* rfs  = (const float*)d_in[1];
    const float* latw = (const float*)d_in[2];
    const float* ada  = (const float*)d_in[3];
    float* out = (float*)d_out;
    float* ws  = (float*)d_ws;

    k_init<<<1, 1024, 0, stream>>>(ws);
    k_aff<<<ANBLK, ABLK, 0, stream>>>(x, rfs, ada, out, ws);

    // ping-pong lat buffers to avoid cross-block read/write race
    for (int t = 0; t < N_ITERS; ++t) {
        const float* src = ws + ((t & 1) ? WS_L1 : WS_L0);
        float* dst = (t == N_ITERS - 1) ? (out + LTOT)
                                        : (ws + ((t & 1) ? WS_L0 : WS_L1));
        if (t == 0) k_lat<true ><<<GRID_L, BLK, 0, stream>>>(latw, ws, src, dst);
        else        k_lat<false><<<GRID_L, BLK, 0, stream>>>(latw, ws, src, dst);
    }

    k_hebb<<<GRID_L, BLK, 0, stream>>>(latw, ws);
    k_final<<<1, 1024, 0, stream>>>(ws, out + 2 * LTOT);
}